// Round 7
// baseline (79.061 us; speedup 1.0000x reference)
//
#include <hip/hip_runtime.h>

// EKF_v2: B=16384, N=128, DX=5, DZ=2.
// R6 structure + (a) per-particle interleaved layer1->layer2/3 (h1 live range
// 64->16 VGPR, occupancy 4->6-7 waves/SIMD), (b) nw1 pre-transposed in d_ws
// (float4 loads, -96 VMEM issues/thread). Same arithmetic order as R6.
// One block = 4 batches, 128 threads; group = 32 lanes, 4 particles/thread.

#define NBPB 4
#define WSJ 32  // floats per packed j-block (128 B aligned)

__global__ __launch_bounds__(256) void pack_w(
    const float* __restrict__ pw2, const float* __restrict__ pb2,
    const float* __restrict__ pw3, const float* __restrict__ nw1,
    float* __restrict__ wp, float* __restrict__ nw1t)
{
    const int t = threadIdx.x;
    // wp[j*32 + r]: r<16 -> pw2[r][j]; r==16 -> pb2[j]; r==17,18 -> pw3[2j+r-17]
    for (int idx = t; idx < 32 * 19; idx += 256) {
        int j = idx / 19, r = idx % 19;
        float v;
        if (r < 16)       v = pw2[r * 32 + j];
        else if (r == 16) v = pb2[j];
        else              v = pw3[2 * j + (r - 17)];
        wp[j * WSJ + r] = v;
    }
    // nw1t[j][k] = nw1[k][j]  (32 x 128)
    for (int idx = t; idx < 4096; idx += 256) {
        int j = idx >> 7, k = idx & 127;
        nw1t[idx] = nw1[k * 32 + j];
    }
}

__global__ __launch_bounds__(128) void ekf_fused(
    const float* __restrict__ state_old,  // (B,128,5)
    const float* __restrict__ y_obs,      // (B,128,2)
    const float* __restrict__ encoding,   // (B,128)
    const float* __restrict__ pw1,        // (2,16)
    const float* __restrict__ pb1,        // (16)
    const float* __restrict__ pb3,        // (2)
    const float* __restrict__ nb1,        // (32)
    const float* __restrict__ nw2,        // (32,2)
    const float* __restrict__ nb2,        // (2)
    const float* __restrict__ lob,        // (2)
    const float* __restrict__ fob,        // (2)
    const float* __restrict__ wp,         // packed pw2t|pb2|pw3 (32 x 32 f)
    const float* __restrict__ nw1t,       // transposed nw1 (32 x 128 f)
    float* __restrict__ out)              // (B,128,5)
{
    __shared__ __align__(16) float s_state[NBPB * 640];

    const int t = threadIdx.x;
    const int base = blockIdx.x * NBPB;

    // ---- stage state (coalesced float4) ----
    {
        const float4* src = (const float4*)(state_old + (size_t)base * 640);
        float4* dst = (float4*)s_state;
        #pragma unroll
        for (int i = t; i < 640; i += 128) dst[i] = src[i];
    }
    __syncthreads();

    const int g = t >> 5;     // batch within block
    const int j32 = t & 31;   // lane within batch group
    const size_t b = (size_t)base + g;

    // ---- noise MLP: 4 independent chains; enc + nw1t via float4 VMEM ----
    float diag0, diag1;
    {
        const float4* eg4 = (const float4*)(encoding + b * 128);
        const float4* wt4 = (const float4*)(nw1t + j32 * 128);
        float a0 = 0.0f, a1 = 0.0f, a2 = 0.0f, a3 = 0.0f;
        #pragma unroll 8
        for (int kk = 0; kk < 32; ++kk) {
            float4 e4 = eg4[kk];
            float4 w4 = wt4[kk];
            a0 = fmaf(e4.x, w4.x, a0);
            a1 = fmaf(e4.y, w4.y, a1);
            a2 = fmaf(e4.z, w4.z, a2);
            a3 = fmaf(e4.w, w4.w, a3);
        }
        float acc = ((a0 + a1) + (a2 + a3)) + nb1[j32];
        float h = fmaxf(acc, 0.0f);
        float d0 = h * nw2[2 * j32 + 0];
        float d1 = h * nw2[2 * j32 + 1];
        #pragma unroll
        for (int off = 1; off < 32; off <<= 1) {
            d0 += __shfl_xor(d0, off, 64);
            d1 += __shfl_xor(d1, off, 64);
        }
        float e0 = d0 + nb2[0] + lob[0];
        float e1 = d1 + nb2[1] + lob[1];
        diag0 = fmaf(e0, e0, fob[0]);
        diag1 = fmaf(e1, e1, fob[1]);
    }

    // ---- process model + MLP, one particle at a time (h1 live range = 16) ----
    float xp[4][5];
    #pragma unroll
    for (int m = 0; m < 4; ++m) {
        const float* s = s_state + g * 640 + (j32 + 32 * m) * 5;
        float s0 = s[0], s1 = s[1], s2 = s[2], v = s[3], td = s[4];
        float theta = s2 + td;
        xp[m][0] = fmaf(v, __sinf(theta), s0);
        xp[m][1] = fmaf(v, __cosf(theta), s1);
        xp[m][2] = theta;

        float h1[16];
        #pragma unroll
        for (int q = 0; q < 16; ++q)
            h1[q] = fmaxf(0.0f, fmaf(v, pw1[q], fmaf(td, pw1[16 + q], pb1[q])));

        float o3 = 0.0f, o4 = 0.0f;
        #pragma unroll 4
        for (int j = 0; j < 32; ++j) {
            const float* wj = wp + j * WSJ; // uniform -> s_load (K$)
            float acc = wj[16];             // pb2[j]
            #pragma unroll
            for (int k = 0; k < 16; ++k)
                acc = fmaf(h1[k], wj[k], acc);
            float r = fmaxf(acc, 0.0f);
            o3 = fmaf(r, wj[17], o3);
            o4 = fmaf(r, wj[18], o4);
        }
        xp[m][3] = v + o3 + pb3[0];
        xp[m][4] = td + o4 + pb3[1];
    }

    // ---- per-batch means (butterfly over 32 lanes) ----
    float mean[5];
    #pragma unroll
    for (int i = 0; i < 5; ++i) {
        float ps = (xp[0][i] + xp[1][i]) + (xp[2][i] + xp[3][i]);
        #pragma unroll
        for (int off = 1; off < 32; off <<= 1) ps += __shfl_xor(ps, off, 64);
        mean[i] = ps * 0.0078125f; // /128 exact
    }

    float A[4][5];
    #pragma unroll
    for (int m = 0; m < 4; ++m)
        #pragma unroll
        for (int i = 0; i < 5; ++i) A[m][i] = xp[m][i] - mean[i];

    // ---- cross-moments (9 chains; S[4][0] == S[3][1] by symmetry) ----
    float S[5][2];
    #pragma unroll
    for (int i = 0; i < 5; ++i) {
        #pragma unroll
        for (int z = 0; z < 2; ++z) {
            if (i == 4 && z == 0) continue;
            float ps = (A[0][i] * A[0][3 + z] + A[1][i] * A[1][3 + z])
                     + (A[2][i] * A[2][3 + z] + A[3][i] * A[3][3 + z]);
            #pragma unroll
            for (int off = 1; off < 32; off <<= 1) ps += __shfl_xor(ps, off, 64);
            S[i][z] = ps;
        }
    }
    S[4][0] = S[3][1];

    // ---- 2x2 solve: Kt = Pzz^{-1} @ Pxz^T ----
    const float inv_denom = 1.0f / 127.0f;
    float p00 = fmaf(S[3][0], inv_denom, diag0);
    float p01 = S[3][1] * inv_denom;
    float p10 = S[4][0] * inv_denom;
    float p11 = fmaf(S[4][1], inv_denom, diag1);
    float det = p00 * p11 - p01 * p10;
    float rdet = 1.0f / det;
    float Kt0[5], Kt1[5];
    #pragma unroll
    for (int i = 0; i < 5; ++i) {
        float b0 = S[i][0] * inv_denom;
        float b1 = S[i][1] * inv_denom;
        Kt0[i] = (p11 * b0 - p01 * b1) * rdet;
        Kt1[i] = (p00 * b1 - p10 * b0) * rdet;
    }

    // ---- Kalman update: y via float2 VMEM, direct global stores ----
    #pragma unroll
    for (int m = 0; m < 4; ++m) {
        const int p = j32 + 32 * m;
        const float2 yy = *(const float2*)(y_obs + (b * 128 + (size_t)p) * 2);
        float i0 = yy.x - xp[m][3];
        float i1 = yy.y - xp[m][4];
        float* o = out + (b * 128 + (size_t)p) * 5;
        #pragma unroll
        for (int i = 0; i < 5; ++i)
            o[i] = xp[m][i] + i0 * Kt0[i] + i1 * Kt1[i];
    }
}

extern "C" void kernel_launch(void* const* d_in, const int* in_sizes, int n_in,
                              void* d_out, int out_size, void* d_ws, size_t ws_size,
                              hipStream_t stream) {
    const float* state_old = (const float*)d_in[0];
    const float* y_obs     = (const float*)d_in[1];
    const float* encoding  = (const float*)d_in[2];
    const float* pw1 = (const float*)d_in[3];
    const float* pb1 = (const float*)d_in[4];
    const float* pw2 = (const float*)d_in[5];
    const float* pb2 = (const float*)d_in[6];
    const float* pw3 = (const float*)d_in[7];
    const float* pb3 = (const float*)d_in[8];
    const float* nw1 = (const float*)d_in[9];
    const float* nb1 = (const float*)d_in[10];
    const float* nw2 = (const float*)d_in[11];
    const float* nb2 = (const float*)d_in[12];
    const float* lob = (const float*)d_in[13];
    const float* fob = (const float*)d_in[14];
    float* out = (float*)d_out;
    float* wpack = (float*)d_ws;           // 32*32 floats = 4 KB
    float* nw1t  = wpack + 32 * WSJ;       // 32*128 floats = 16 KB

    hipLaunchKernelGGL(pack_w, dim3(1), dim3(256), 0, stream,
                       pw2, pb2, pw3, nw1, wpack, nw1t);

    const int B = 16384;
    dim3 grid(B / NBPB);
    dim3 block(128);
    hipLaunchKernelGGL(ekf_fused, grid, block, 0, stream,
                       state_old, y_obs, encoding,
                       pw1, pb1, pb3,
                       nb1, nw2, nb2, lob, fob, wpack, nw1t, out);
}

// Round 8
// 71.182 us; speedup vs baseline: 1.1107x; 1.1107x over previous
//
#include <hip/hip_runtime.h>

// EKF_v2: B=16384, N=128, DX=5, DZ=2.
// R7 base + (a) particle-PAIR MLP: 4 independent FMA chains (ILP) at ~32 live
// h1 regs, (b) single-phase 14-chain raw-moment reduction (one butterfly
// phase instead of two), (c) pack_w parallelized across 17 blocks.
// One block = 4 batches, 128 threads; group = 32 lanes, 4 particles/thread.

#define NBPB 4
#define WSJ 32  // floats per packed j-block (128 B aligned)

__global__ __launch_bounds__(256) void pack_w(
    const float* __restrict__ pw2, const float* __restrict__ pb2,
    const float* __restrict__ pw3, const float* __restrict__ nw1,
    float* __restrict__ wp, float* __restrict__ nw1t)
{
    const int t = threadIdx.x;
    const int bid = blockIdx.x;
    if (bid == 0) {
        // wp[j*32+r]: r<16 -> pw2[r][j]; r==16 -> pb2[j]; r==17,18 -> pw3[2j+r-17]
        for (int idx = t; idx < 32 * 19; idx += 256) {
            int j = idx / 19, r = idx % 19;
            float v;
            if (r < 16)       v = pw2[r * 32 + j];
            else if (r == 16) v = pb2[j];
            else              v = pw3[2 * j + (r - 17)];
            wp[j * WSJ + r] = v;
        }
    } else {
        // nw1t[j][k] = nw1[k][j]  (32 x 128), one element per thread
        int idx = (bid - 1) * 256 + t;
        nw1t[idx] = nw1[(idx & 127) * 32 + (idx >> 7)];
    }
}

__global__ __launch_bounds__(128) void ekf_fused(
    const float* __restrict__ state_old,  // (B,128,5)
    const float* __restrict__ y_obs,      // (B,128,2)
    const float* __restrict__ encoding,   // (B,128)
    const float* __restrict__ pw1,        // (2,16)
    const float* __restrict__ pb1,        // (16)
    const float* __restrict__ pb3,        // (2)
    const float* __restrict__ nb1,        // (32)
    const float* __restrict__ nw2,        // (32,2)
    const float* __restrict__ nb2,        // (2)
    const float* __restrict__ lob,        // (2)
    const float* __restrict__ fob,        // (2)
    const float* __restrict__ wp,         // packed pw2t|pb2|pw3 (32 x 32 f)
    const float* __restrict__ nw1t,       // transposed nw1 (32 x 128 f)
    float* __restrict__ out)              // (B,128,5)
{
    __shared__ __align__(16) float s_state[NBPB * 640];

    const int t = threadIdx.x;
    const int base = blockIdx.x * NBPB;

    // ---- stage state (coalesced float4) ----
    {
        const float4* src = (const float4*)(state_old + (size_t)base * 640);
        float4* dst = (float4*)s_state;
        #pragma unroll
        for (int i = t; i < 640; i += 128) dst[i] = src[i];
    }
    __syncthreads();

    const int g = t >> 5;     // batch within block
    const int j32 = t & 31;   // lane within batch group
    const size_t b = (size_t)base + g;

    // ---- noise MLP: 4 independent chains; enc + nw1t via float4 VMEM ----
    float diag0, diag1;
    {
        const float4* eg4 = (const float4*)(encoding + b * 128);
        const float4* wt4 = (const float4*)(nw1t + j32 * 128);
        float a0 = 0.0f, a1 = 0.0f, a2 = 0.0f, a3 = 0.0f;
        #pragma unroll 8
        for (int kk = 0; kk < 32; ++kk) {
            float4 e4 = eg4[kk];
            float4 w4 = wt4[kk];
            a0 = fmaf(e4.x, w4.x, a0);
            a1 = fmaf(e4.y, w4.y, a1);
            a2 = fmaf(e4.z, w4.z, a2);
            a3 = fmaf(e4.w, w4.w, a3);
        }
        float acc = ((a0 + a1) + (a2 + a3)) + nb1[j32];
        float h = fmaxf(acc, 0.0f);
        float d0 = h * nw2[2 * j32 + 0];
        float d1 = h * nw2[2 * j32 + 1];
        #pragma unroll
        for (int off = 1; off < 32; off <<= 1) {
            d0 += __shfl_xor(d0, off, 64);
            d1 += __shfl_xor(d1, off, 64);
        }
        float e0 = d0 + nb2[0] + lob[0];
        float e1 = d1 + nb2[1] + lob[1];
        diag0 = fmaf(e0, e0, fob[0]);
        diag1 = fmaf(e1, e1, fob[1]);
    }

    // ---- process model + MLP in particle PAIRS (4 indep chains in j-loop) ----
    float xp[4][5];
    #pragma unroll
    for (int mp = 0; mp < 2; ++mp) {
        const int m0 = 2 * mp, m1 = 2 * mp + 1;
        const float* sA = s_state + g * 640 + (j32 + 32 * m0) * 5;
        const float* sB = s_state + g * 640 + (j32 + 32 * m1) * 5;
        float vA = sA[3], tdA = sA[4], thA = sA[2] + tdA;
        float vB = sB[3], tdB = sB[4], thB = sB[2] + tdB;
        xp[m0][0] = fmaf(vA, __sinf(thA), sA[0]);
        xp[m0][1] = fmaf(vA, __cosf(thA), sA[1]);
        xp[m0][2] = thA;
        xp[m1][0] = fmaf(vB, __sinf(thB), sB[0]);
        xp[m1][1] = fmaf(vB, __cosf(thB), sB[1]);
        xp[m1][2] = thB;

        float h1a[16], h1b[16];
        #pragma unroll
        for (int q = 0; q < 16; ++q) {
            float w0 = pw1[q], w1 = pw1[16 + q], bq = pb1[q];
            h1a[q] = fmaxf(0.0f, fmaf(vA, w0, fmaf(tdA, w1, bq)));
            h1b[q] = fmaxf(0.0f, fmaf(vB, w0, fmaf(tdB, w1, bq)));
        }

        float o3a = 0.0f, o4a = 0.0f, o3b = 0.0f, o4b = 0.0f;
        #pragma unroll 2
        for (int j = 0; j < 32; ++j) {
            const float* wj = wp + j * WSJ; // uniform -> s_load (K$)
            float acca = wj[16];            // pb2[j]
            float accb = acca;
            #pragma unroll
            for (int k = 0; k < 16; ++k) {
                float wk = wj[k];
                acca = fmaf(h1a[k], wk, acca);
                accb = fmaf(h1b[k], wk, accb);
            }
            float w30 = wj[17], w31 = wj[18];
            float ra = fmaxf(acca, 0.0f), rb = fmaxf(accb, 0.0f);
            o3a = fmaf(ra, w30, o3a);
            o4a = fmaf(ra, w31, o4a);
            o3b = fmaf(rb, w30, o3b);
            o4b = fmaf(rb, w31, o4b);
        }
        xp[m0][3] = vA + o3a + pb3[0];
        xp[m0][4] = tdA + o4a + pb3[1];
        xp[m1][3] = vB + o3b + pb3[0];
        xp[m1][4] = tdB + o4b + pb3[1];
    }

    // ---- raw moments: ONE butterfly phase, 14 independent chains ----
    // red[0..4] = sum_p xp_i ; red[5..13] = sum_p xp_i*xp_{3+z} for
    // (i,z) in (0,0)(0,1)(1,0)(1,1)(2,0)(2,1)(3,0)(3,1)(4,1); (4,0)==(3,1)
    float red[14];
    #pragma unroll
    for (int i = 0; i < 5; ++i)
        red[i] = (xp[0][i] + xp[1][i]) + (xp[2][i] + xp[3][i]);
    {
        int r = 5;
        #pragma unroll
        for (int i = 0; i < 5; ++i) {
            #pragma unroll
            for (int z = 0; z < 2; ++z) {
                if (i == 4 && z == 0) continue;
                red[r++] = (xp[0][i] * xp[0][3 + z] + xp[1][i] * xp[1][3 + z])
                         + (xp[2][i] * xp[2][3 + z] + xp[3][i] * xp[3][3 + z]);
            }
        }
    }
    #pragma unroll
    for (int off = 1; off < 32; off <<= 1) {
        #pragma unroll
        for (int r = 0; r < 14; ++r)
            red[r] += __shfl_xor(red[r], off, 64);
    }

    // ---- covariances from raw moments + analytic 2x2 solve ----
    const float inv  = 1.0f / 127.0f;
    const float minv = inv * 0.0078125f; // 1/(127*128)
    float S[5][2];
    {
        int r = 5;
        #pragma unroll
        for (int i = 0; i < 5; ++i) {
            #pragma unroll
            for (int z = 0; z < 2; ++z) {
                if (i == 4 && z == 0) continue;
                S[i][z] = red[r++] * inv - red[i] * red[3 + z] * minv;
            }
        }
        S[4][0] = S[3][1];
    }
    float p00 = S[3][0] + diag0;
    float p01 = S[3][1];
    float p10 = S[4][0];
    float p11 = S[4][1] + diag1;
    float rdet = 1.0f / (p00 * p11 - p01 * p10);
    float Kt0[5], Kt1[5];
    #pragma unroll
    for (int i = 0; i < 5; ++i) {
        Kt0[i] = (p11 * S[i][0] - p01 * S[i][1]) * rdet;
        Kt1[i] = (p00 * S[i][1] - p10 * S[i][0]) * rdet;
    }

    // ---- Kalman update: y via float2 VMEM, direct global stores ----
    #pragma unroll
    for (int m = 0; m < 4; ++m) {
        const int p = j32 + 32 * m;
        const float2 yy = *(const float2*)(y_obs + (b * 128 + (size_t)p) * 2);
        float i0 = yy.x - xp[m][3];
        float i1 = yy.y - xp[m][4];
        float* o = out + (b * 128 + (size_t)p) * 5;
        #pragma unroll
        for (int i = 0; i < 5; ++i)
            o[i] = xp[m][i] + i0 * Kt0[i] + i1 * Kt1[i];
    }
}

extern "C" void kernel_launch(void* const* d_in, const int* in_sizes, int n_in,
                              void* d_out, int out_size, void* d_ws, size_t ws_size,
                              hipStream_t stream) {
    const float* state_old = (const float*)d_in[0];
    const float* y_obs     = (const float*)d_in[1];
    const float* encoding  = (const float*)d_in[2];
    const float* pw1 = (const float*)d_in[3];
    const float* pb1 = (const float*)d_in[4];
    const float* pw2 = (const float*)d_in[5];
    const float* pb2 = (const float*)d_in[6];
    const float* pw3 = (const float*)d_in[7];
    const float* pb3 = (const float*)d_in[8];
    const float* nw1 = (const float*)d_in[9];
    const float* nb1 = (const float*)d_in[10];
    const float* nw2 = (const float*)d_in[11];
    const float* nb2 = (const float*)d_in[12];
    const float* lob = (const float*)d_in[13];
    const float* fob = (const float*)d_in[14];
    float* out = (float*)d_out;
    float* wpack = (float*)d_ws;           // 32*32 floats = 4 KB
    float* nw1t  = wpack + 32 * WSJ;       // 32*128 floats = 16 KB

    hipLaunchKernelGGL(pack_w, dim3(17), dim3(256), 0, stream,
                       pw2, pb2, pw3, nw1, wpack, nw1t);

    const int B = 16384;
    dim3 grid(B / NBPB);
    dim3 block(128);
    hipLaunchKernelGGL(ekf_fused, grid, block, 0, stream,
                       state_old, y_obs, encoding,
                       pw1, pb1, pb3,
                       nb1, nw2, nb2, lob, fob, wpack, nw1t, out);
}

// Round 9
// 67.147 us; speedup vs baseline: 1.1774x; 1.0601x over previous
//
#include <hip/hip_runtime.h>

// EKF_v2: B=16384, N=128, DX=5, DZ=2.
// Wave = one batch (64 lanes). Layer-2 of the process MLP (16->32, the
// dominant ~2048 FMA/thread) moved to MFMA v_mfma_f32_32x32x16_bf16:
// 4 MFMAs/wave replace ~4096 VALU cycles. Lane l supplies the h1 k-slice
// (k=8*(l>>5)+q) for particle (l&31)+32m  == the B fragment; A = pw2^T bf16
// prepacked in d_ws; C-init = pb2 (bias free). Epilogue (32->2) on VALU from
// the verified C/D layout (col=lane&31, row=(reg&3)+8*(reg>>2)+4*(lane>>5)).
// Ownership for reductions/stores: half h owns m = 2h, 2h+1 (2 particles/lane).

#define NBPB 4  // batches (=waves) per block

typedef __bf16 bf16x8 __attribute__((ext_vector_type(8)));
typedef float  f32x16 __attribute__((ext_vector_type(16)));

__global__ __launch_bounds__(256) void pack_w(
    const float* __restrict__ pw2, const float* __restrict__ nw1,
    unsigned short* __restrict__ wA, float* __restrict__ nw1t)
{
    const int t = threadIdx.x;
    const int bid = blockIdx.x;
    if (bid < 16) {
        int idx = bid * 256 + t;                    // 0..4095
        nw1t[idx] = nw1[(idx & 127) * 32 + (idx >> 7)];
    } else {
        // wA[l*8+q] = bf16(pw2[k][row]), row=l&31, k=8*(l>>5)+q
        for (int idx = t; idx < 512; idx += 256) {
            int l = idx >> 3, q = idx & 7;
            int row = l & 31, k = 8 * (l >> 5) + q;
            __bf16 v = (__bf16)pw2[k * 32 + row];
            wA[idx] = __builtin_bit_cast(unsigned short, v);
        }
    }
}

__global__ __launch_bounds__(256) void ekf_fused(
    const float* __restrict__ state_old,  // (B,128,5)
    const float* __restrict__ y_obs,      // (B,128,2)
    const float* __restrict__ encoding,   // (B,128)
    const float* __restrict__ pw1,        // (2,16)
    const float* __restrict__ pb1,        // (16)
    const float* __restrict__ pb2,        // (32)
    const float* __restrict__ pw3,        // (32,2)
    const float* __restrict__ pb3,        // (2)
    const float* __restrict__ nb1,        // (32)
    const float* __restrict__ nw2,        // (32,2)
    const float* __restrict__ nb2,        // (2)
    const float* __restrict__ lob,        // (2)
    const float* __restrict__ fob,        // (2)
    const unsigned short* __restrict__ wA,// A-fragment pack (64 x 8 bf16)
    const float* __restrict__ nw1t,       // nw1 transposed (32 x 128)
    float* __restrict__ out)              // (B,128,5)
{
    __shared__ __align__(16) float s_state[NBPB * 640];

    const int t = threadIdx.x;
    const int base = blockIdx.x * NBPB;

    // ---- stage state (coalesced float4) ----
    {
        const float4* src = (const float4*)(state_old + (size_t)base * 640);
        float4* dst = (float4*)s_state;
        #pragma unroll
        for (int i = t; i < NBPB * 160; i += 256) dst[i] = src[i];
    }
    __syncthreads();

    const int w = t >> 6;    // wave = batch within block
    const int l = t & 63;
    const int c = l & 31;    // column / particle-in-group
    const int h = l >> 5;    // lane half -> k-slice & ownership
    const size_t b = (size_t)base + w;

    // ---- noise MLP: j = c, k-range split across halves ----
    float diag0, diag1;
    {
        const float4* eg4 = (const float4*)(encoding + b * 128) + h * 16;
        const float4* wt4 = (const float4*)(nw1t + c * 128) + h * 16;
        float a0 = 0.f, a1 = 0.f, a2 = 0.f, a3 = 0.f;
        #pragma unroll
        for (int kk = 0; kk < 16; ++kk) {
            float4 e4 = eg4[kk]; float4 w4 = wt4[kk];
            a0 = fmaf(e4.x, w4.x, a0);
            a1 = fmaf(e4.y, w4.y, a1);
            a2 = fmaf(e4.z, w4.z, a2);
            a3 = fmaf(e4.w, w4.w, a3);
        }
        float acc = (a0 + a1) + (a2 + a3);
        acc += __shfl_xor(acc, 32, 64);   // combine k-halves
        acc += nb1[c];
        float hh = fmaxf(acc, 0.f);
        float d0 = hh * nw2[2 * c + 0];
        float d1 = hh * nw2[2 * c + 1];
        #pragma unroll
        for (int off = 1; off < 32; off <<= 1) {
            d0 += __shfl_xor(d0, off, 64);
            d1 += __shfl_xor(d1, off, 64);
        }
        float e0 = d0 + nb2[0] + lob[0];
        float e1 = d1 + nb2[1] + lob[1];
        diag0 = fmaf(e0, e0, fob[0]);
        diag1 = fmaf(e1, e1, fob[1]);
    }

    // ---- per-half tables (L1 broadcast loads) ----
    const float4 pw1a0 = *(const float4*)(pw1 + 8 * h);
    const float4 pw1a1 = *(const float4*)(pw1 + 8 * h + 4);
    const float4 pw1b0 = *(const float4*)(pw1 + 16 + 8 * h);
    const float4 pw1b1 = *(const float4*)(pw1 + 16 + 8 * h + 4);
    const float4 pb1k0 = *(const float4*)(pb1 + 8 * h);
    const float4 pb1k1 = *(const float4*)(pb1 + 8 * h + 4);
    float4 pb2v[4], pw3lo[4], pw3hi[4];
    #pragma unroll
    for (int gr = 0; gr < 4; ++gr) {
        pb2v[gr]  = *(const float4*)(pb2 + 8 * gr + 4 * h);
        pw3lo[gr] = *(const float4*)(pw3 + 16 * gr + 8 * h);
        pw3hi[gr] = *(const float4*)(pw3 + 16 * gr + 8 * h + 4);
    }
    const bf16x8 afrag = *(const bf16x8*)(wA + l * 8);
    f32x16 cinit;
    #pragma unroll
    for (int gr = 0; gr < 4; ++gr) {
        cinit[4 * gr + 0] = pb2v[gr].x;
        cinit[4 * gr + 1] = pb2v[gr].y;
        cinit[4 * gr + 2] = pb2v[gr].z;
        cinit[4 * gr + 3] = pb2v[gr].w;
    }

    // ---- process MLP via MFMA: per m, B = h1 k-slices; D = pw2^T@h1 + pb2 ----
    const float* sp = s_state + w * 640;
    float o3m[4], o4m[4];
    #pragma unroll
    for (int m = 0; m < 4; ++m) {
        const float* s5 = sp + (c + 32 * m) * 5;
        float v = s5[3], td = s5[4];
        bf16x8 bfrag;
        bfrag[0] = (__bf16)fmaxf(0.f, fmaf(v, pw1a0.x, fmaf(td, pw1b0.x, pb1k0.x)));
        bfrag[1] = (__bf16)fmaxf(0.f, fmaf(v, pw1a0.y, fmaf(td, pw1b0.y, pb1k0.y)));
        bfrag[2] = (__bf16)fmaxf(0.f, fmaf(v, pw1a0.z, fmaf(td, pw1b0.z, pb1k0.z)));
        bfrag[3] = (__bf16)fmaxf(0.f, fmaf(v, pw1a0.w, fmaf(td, pw1b0.w, pb1k0.w)));
        bfrag[4] = (__bf16)fmaxf(0.f, fmaf(v, pw1a1.x, fmaf(td, pw1b1.x, pb1k1.x)));
        bfrag[5] = (__bf16)fmaxf(0.f, fmaf(v, pw1a1.y, fmaf(td, pw1b1.y, pb1k1.y)));
        bfrag[6] = (__bf16)fmaxf(0.f, fmaf(v, pw1a1.z, fmaf(td, pw1b1.z, pb1k1.z)));
        bfrag[7] = (__bf16)fmaxf(0.f, fmaf(v, pw1a1.w, fmaf(td, pw1b1.w, pb1k1.w)));
        f32x16 acc = __builtin_amdgcn_mfma_f32_32x32x16_bf16(afrag, bfrag, cinit, 0, 0, 0);
        float o3 = 0.f, o4 = 0.f;
        #pragma unroll
        for (int gr = 0; gr < 4; ++gr) {
            float r0 = fmaxf(acc[4 * gr + 0], 0.f);
            float r1 = fmaxf(acc[4 * gr + 1], 0.f);
            float r2 = fmaxf(acc[4 * gr + 2], 0.f);
            float r3 = fmaxf(acc[4 * gr + 3], 0.f);
            o3 = fmaf(r0, pw3lo[gr].x, o3); o4 = fmaf(r0, pw3lo[gr].y, o4);
            o3 = fmaf(r1, pw3lo[gr].z, o3); o4 = fmaf(r1, pw3lo[gr].w, o4);
            o3 = fmaf(r2, pw3hi[gr].x, o3); o4 = fmaf(r2, pw3hi[gr].y, o4);
            o3 = fmaf(r3, pw3hi[gr].z, o3); o4 = fmaf(r3, pw3hi[gr].w, o4);
        }
        o3m[m] = o3; o4m[m] = o4;
    }
    #pragma unroll
    for (int m = 0; m < 4; ++m) {
        o3m[m] += __shfl_xor(o3m[m], 32, 64);  // combine h2-row halves
        o4m[m] += __shfl_xor(o4m[m], 32, 64);
    }

    // ---- owned particles (half h owns m = 2h, 2h+1) ----
    const float pb30 = pb3[0], pb31 = pb3[1];
    float o3s0 = h ? o3m[2] : o3m[0];
    float o3s1 = h ? o3m[3] : o3m[1];
    float o4s0 = h ? o4m[2] : o4m[0];
    float o4s1 = h ? o4m[3] : o4m[1];
    float xpo[2][5];
    #pragma unroll
    for (int mm = 0; mm < 2; ++mm) {
        const float* s5 = sp + (c + 32 * (2 * h + mm)) * 5;
        float s0 = s5[0], s1 = s5[1], s2 = s5[2], v = s5[3], td = s5[4];
        float th = s2 + td;
        xpo[mm][0] = fmaf(v, __sinf(th), s0);
        xpo[mm][1] = fmaf(v, __cosf(th), s1);
        xpo[mm][2] = th;
        xpo[mm][3] = v  + (mm ? o3s1 : o3s0) + pb30;
        xpo[mm][4] = td + (mm ? o4s1 : o4s0) + pb31;
    }

    // ---- raw moments: ONE butterfly phase (6 levels), 14 chains ----
    float red[14];
    #pragma unroll
    for (int i = 0; i < 5; ++i) red[i] = xpo[0][i] + xpo[1][i];
    red[5]  = xpo[0][0] * xpo[0][3] + xpo[1][0] * xpo[1][3];
    red[6]  = xpo[0][0] * xpo[0][4] + xpo[1][0] * xpo[1][4];
    red[7]  = xpo[0][1] * xpo[0][3] + xpo[1][1] * xpo[1][3];
    red[8]  = xpo[0][1] * xpo[0][4] + xpo[1][1] * xpo[1][4];
    red[9]  = xpo[0][2] * xpo[0][3] + xpo[1][2] * xpo[1][3];
    red[10] = xpo[0][2] * xpo[0][4] + xpo[1][2] * xpo[1][4];
    red[11] = xpo[0][3] * xpo[0][3] + xpo[1][3] * xpo[1][3];
    red[12] = xpo[0][3] * xpo[0][4] + xpo[1][3] * xpo[1][4];
    red[13] = xpo[0][4] * xpo[0][4] + xpo[1][4] * xpo[1][4];
    #pragma unroll
    for (int off = 1; off < 64; off <<= 1) {
        #pragma unroll
        for (int r = 0; r < 14; ++r)
            red[r] += __shfl_xor(red[r], off, 64);
    }

    // ---- covariances + analytic 2x2 solve ----
    const float inv  = 1.0f / 127.0f;
    const float minv = inv * 0.0078125f; // 1/(127*128)
    float S00 = red[5]  * inv - red[0] * red[3] * minv;
    float S01 = red[6]  * inv - red[0] * red[4] * minv;
    float S10 = red[7]  * inv - red[1] * red[3] * minv;
    float S11 = red[8]  * inv - red[1] * red[4] * minv;
    float S20 = red[9]  * inv - red[2] * red[3] * minv;
    float S21 = red[10] * inv - red[2] * red[4] * minv;
    float S30 = red[11] * inv - red[3] * red[3] * minv;
    float S31 = red[12] * inv - red[3] * red[4] * minv;
    float S40 = S31;
    float S41 = red[13] * inv - red[4] * red[4] * minv;
    float p00 = S30 + diag0, p01 = S31, p10 = S40, p11 = S41 + diag1;
    float rdet = 1.0f / (p00 * p11 - p01 * p10);
    float Ka0 = (p11 * S00 - p01 * S01) * rdet, Kb0 = (p00 * S01 - p10 * S00) * rdet;
    float Ka1 = (p11 * S10 - p01 * S11) * rdet, Kb1 = (p00 * S11 - p10 * S10) * rdet;
    float Ka2 = (p11 * S20 - p01 * S21) * rdet, Kb2 = (p00 * S21 - p10 * S20) * rdet;
    float Ka3 = (p11 * S30 - p01 * S31) * rdet, Kb3 = (p00 * S31 - p10 * S30) * rdet;
    float Ka4 = (p11 * S40 - p01 * S41) * rdet, Kb4 = (p00 * S41 - p10 * S40) * rdet;

    // ---- Kalman update + direct stores (2 owned particles) ----
    #pragma unroll
    for (int mm = 0; mm < 2; ++mm) {
        const int p = c + 32 * (2 * h + mm);
        const float2 yy = *(const float2*)(y_obs + (b * 128 + (size_t)p) * 2);
        float i0 = yy.x - xpo[mm][3];
        float i1 = yy.y - xpo[mm][4];
        float* o = out + (b * 128 + (size_t)p) * 5;
        o[0] = xpo[mm][0] + i0 * Ka0 + i1 * Kb0;
        o[1] = xpo[mm][1] + i0 * Ka1 + i1 * Kb1;
        o[2] = xpo[mm][2] + i0 * Ka2 + i1 * Kb2;
        o[3] = xpo[mm][3] + i0 * Ka3 + i1 * Kb3;
        o[4] = xpo[mm][4] + i0 * Ka4 + i1 * Kb4;
    }
}

extern "C" void kernel_launch(void* const* d_in, const int* in_sizes, int n_in,
                              void* d_out, int out_size, void* d_ws, size_t ws_size,
                              hipStream_t stream) {
    const float* state_old = (const float*)d_in[0];
    const float* y_obs     = (const float*)d_in[1];
    const float* encoding  = (const float*)d_in[2];
    const float* pw1 = (const float*)d_in[3];
    const float* pb1 = (const float*)d_in[4];
    const float* pw2 = (const float*)d_in[5];
    const float* pb2 = (const float*)d_in[6];
    const float* pw3 = (const float*)d_in[7];
    const float* pb3 = (const float*)d_in[8];
    const float* nw1 = (const float*)d_in[9];
    const float* nb1 = (const float*)d_in[10];
    const float* nw2 = (const float*)d_in[11];
    const float* nb2 = (const float*)d_in[12];
    const float* lob = (const float*)d_in[13];
    const float* fob = (const float*)d_in[14];
    float* out = (float*)d_out;

    unsigned short* wA = (unsigned short*)d_ws;               // 512 ushort = 1 KB
    float* nw1t = (float*)((char*)d_ws + 1024);               // 4096 f = 16 KB

    hipLaunchKernelGGL(pack_w, dim3(17), dim3(256), 0, stream, pw2, nw1, wA, nw1t);

    const int B = 16384;
    dim3 grid(B / NBPB);
    dim3 block(256);
    hipLaunchKernelGGL(ekf_fused, grid, block, 0, stream,
                       state_old, y_obs, encoding,
                       pw1, pb1, pb2, pw3, pb3,
                       nb1, nw2, nb2, lob, fob, wA, nw1t, out);
}

// Round 13
// 43.390 us; speedup vs baseline: 1.8221x; 1.5475x over previous
//
#include <hip/hip_runtime.h>

// EKF_v2: B=16384, N=128, DX=5, DZ=2.
// R9's passing kernel (wave=batch, layer-2 via v_mfma_f32_32x32x16_bf16,
// 67us) made SELF-CONTAINED: no pack_w, no d_ws. R12's failure was in
// post-timing re-validation with R9-identical numerics -> the pack_w->d_ws
// ->ekf_fused cross-kernel channel is the fragile element; removed.
//  - afrag built in-kernel from pw2 (8 coalesced loads, same bf16 convert)
//  - noise MLP reads nw1 directly (coalesced dwords), same chain order as R9.

#define NBPB 4  // batches (=waves) per block

typedef __bf16 bf16x8 __attribute__((ext_vector_type(8)));
typedef float  f32x16 __attribute__((ext_vector_type(16)));

__global__ __launch_bounds__(256) void ekf_fused(
    const float* __restrict__ state_old,  // (B,128,5)
    const float* __restrict__ y_obs,      // (B,128,2)
    const float* __restrict__ encoding,   // (B,128)
    const float* __restrict__ pw1,        // (2,16)
    const float* __restrict__ pb1,        // (16)
    const float* __restrict__ pw2,        // (16,32)
    const float* __restrict__ pb2,        // (32)
    const float* __restrict__ pw3,        // (32,2)
    const float* __restrict__ pb3,        // (2)
    const float* __restrict__ nw1,        // (128,32)
    const float* __restrict__ nb1,        // (32)
    const float* __restrict__ nw2,        // (32,2)
    const float* __restrict__ nb2,        // (2)
    const float* __restrict__ lob,        // (2)
    const float* __restrict__ fob,        // (2)
    float* __restrict__ out)              // (B,128,5)
{
    __shared__ __align__(16) float s_state[NBPB * 640];

    const int t = threadIdx.x;
    const int base = blockIdx.x * NBPB;

    // ---- stage state (coalesced float4) ----
    {
        const float4* src = (const float4*)(state_old + (size_t)base * 640);
        float4* dst = (float4*)s_state;
        #pragma unroll
        for (int i = t; i < NBPB * 160; i += 256) dst[i] = src[i];
    }
    __syncthreads();

    const int w = t >> 6;    // wave = batch within block
    const int l = t & 63;
    const int c = l & 31;    // column / particle-in-group
    const int h = l >> 5;    // lane half -> k-slice & ownership
    const size_t b = (size_t)base + w;

    // ---- noise MLP: j = c, k-range split across halves (R9 chain order) ----
    float diag0, diag1;
    {
        const float4* eg4 = (const float4*)(encoding + b * 128) + h * 16;
        const float* wp = nw1 + (size_t)(h * 64) * 32 + c; // k = h*64 + 4*kk + r
        float a0 = 0.f, a1 = 0.f, a2 = 0.f, a3 = 0.f;
        #pragma unroll
        for (int kk = 0; kk < 16; ++kk) {
            float4 e4 = eg4[kk];
            a0 = fmaf(e4.x, wp[(4 * kk + 0) * 32], a0);
            a1 = fmaf(e4.y, wp[(4 * kk + 1) * 32], a1);
            a2 = fmaf(e4.z, wp[(4 * kk + 2) * 32], a2);
            a3 = fmaf(e4.w, wp[(4 * kk + 3) * 32], a3);
        }
        float acc = (a0 + a1) + (a2 + a3);
        acc += __shfl_xor(acc, 32, 64);   // combine k-halves
        acc += nb1[c];
        float hh = fmaxf(acc, 0.f);
        float d0 = hh * nw2[2 * c + 0];
        float d1 = hh * nw2[2 * c + 1];
        #pragma unroll
        for (int off = 1; off < 32; off <<= 1) {
            d0 += __shfl_xor(d0, off, 64);
            d1 += __shfl_xor(d1, off, 64);
        }
        float e0 = d0 + nb2[0] + lob[0];
        float e1 = d1 + nb2[1] + lob[1];
        diag0 = fmaf(e0, e0, fob[0]);
        diag1 = fmaf(e1, e1, fob[1]);
    }

    // ---- per-half layer-1 tables (L1 broadcast loads) ----
    const float4 pw1a0 = *(const float4*)(pw1 + 8 * h);
    const float4 pw1a1 = *(const float4*)(pw1 + 8 * h + 4);
    const float4 pw1b0 = *(const float4*)(pw1 + 16 + 8 * h);
    const float4 pw1b1 = *(const float4*)(pw1 + 16 + 8 * h + 4);
    const float4 pb1k0 = *(const float4*)(pb1 + 8 * h);
    const float4 pb1k1 = *(const float4*)(pb1 + 8 * h + 4);
    float4 pb2v[4], pw3lo[4], pw3hi[4];
    #pragma unroll
    for (int gr = 0; gr < 4; ++gr) {
        pb2v[gr]  = *(const float4*)(pb2 + 8 * gr + 4 * h);
        pw3lo[gr] = *(const float4*)(pw3 + 16 * gr + 8 * h);
        pw3hi[gr] = *(const float4*)(pw3 + 16 * gr + 8 * h + 4);
    }
    // A-fragment from pw2 directly: afr[q] = bf16(pw2[(8h+q)*32 + c])
    bf16x8 afrag;
    #pragma unroll
    for (int q = 0; q < 8; ++q)
        afrag[q] = (__bf16)pw2[(8 * h + q) * 32 + c];
    f32x16 cinit;
    #pragma unroll
    for (int gr = 0; gr < 4; ++gr) {
        cinit[4 * gr + 0] = pb2v[gr].x;
        cinit[4 * gr + 1] = pb2v[gr].y;
        cinit[4 * gr + 2] = pb2v[gr].z;
        cinit[4 * gr + 3] = pb2v[gr].w;
    }

    // ---- process MLP via MFMA: per m, B = h1 k-slices; D = pw2^T@h1 + pb2 ----
    const float* sp = s_state + w * 640;
    float o3m[4], o4m[4];
    #pragma unroll
    for (int m = 0; m < 4; ++m) {
        const float* s5 = sp + (c + 32 * m) * 5;
        float v = s5[3], td = s5[4];
        bf16x8 bfrag;
        bfrag[0] = (__bf16)fmaxf(0.f, fmaf(v, pw1a0.x, fmaf(td, pw1b0.x, pb1k0.x)));
        bfrag[1] = (__bf16)fmaxf(0.f, fmaf(v, pw1a0.y, fmaf(td, pw1b0.y, pb1k0.y)));
        bfrag[2] = (__bf16)fmaxf(0.f, fmaf(v, pw1a0.z, fmaf(td, pw1b0.z, pb1k0.z)));
        bfrag[3] = (__bf16)fmaxf(0.f, fmaf(v, pw1a0.w, fmaf(td, pw1b0.w, pb1k0.w)));
        bfrag[4] = (__bf16)fmaxf(0.f, fmaf(v, pw1a1.x, fmaf(td, pw1b1.x, pb1k1.x)));
        bfrag[5] = (__bf16)fmaxf(0.f, fmaf(v, pw1a1.y, fmaf(td, pw1b1.y, pb1k1.y)));
        bfrag[6] = (__bf16)fmaxf(0.f, fmaf(v, pw1a1.z, fmaf(td, pw1b1.z, pb1k1.z)));
        bfrag[7] = (__bf16)fmaxf(0.f, fmaf(v, pw1a1.w, fmaf(td, pw1b1.w, pb1k1.w)));
        f32x16 acc = __builtin_amdgcn_mfma_f32_32x32x16_bf16(afrag, bfrag, cinit, 0, 0, 0);
        float o3 = 0.f, o4 = 0.f;
        #pragma unroll
        for (int gr = 0; gr < 4; ++gr) {
            float r0 = fmaxf(acc[4 * gr + 0], 0.f);
            float r1 = fmaxf(acc[4 * gr + 1], 0.f);
            float r2 = fmaxf(acc[4 * gr + 2], 0.f);
            float r3 = fmaxf(acc[4 * gr + 3], 0.f);
            o3 = fmaf(r0, pw3lo[gr].x, o3); o4 = fmaf(r0, pw3lo[gr].y, o4);
            o3 = fmaf(r1, pw3lo[gr].z, o3); o4 = fmaf(r1, pw3lo[gr].w, o4);
            o3 = fmaf(r2, pw3hi[gr].x, o3); o4 = fmaf(r2, pw3hi[gr].y, o4);
            o3 = fmaf(r3, pw3hi[gr].z, o3); o4 = fmaf(r3, pw3hi[gr].w, o4);
        }
        o3m[m] = o3; o4m[m] = o4;
    }
    #pragma unroll
    for (int m = 0; m < 4; ++m) {
        o3m[m] += __shfl_xor(o3m[m], 32, 64);  // combine h2-row halves
        o4m[m] += __shfl_xor(o4m[m], 32, 64);
    }

    // ---- owned particles (half h owns m = 2h, 2h+1) ----
    const float pb30 = pb3[0], pb31 = pb3[1];
    float o3s0 = h ? o3m[2] : o3m[0];
    float o3s1 = h ? o3m[3] : o3m[1];
    float o4s0 = h ? o4m[2] : o4m[0];
    float o4s1 = h ? o4m[3] : o4m[1];
    float xpo[2][5];
    #pragma unroll
    for (int mm = 0; mm < 2; ++mm) {
        const float* s5 = sp + (c + 32 * (2 * h + mm)) * 5;
        float s0 = s5[0], s1 = s5[1], s2 = s5[2], v = s5[3], td = s5[4];
        float th = s2 + td;
        xpo[mm][0] = fmaf(v, __sinf(th), s0);
        xpo[mm][1] = fmaf(v, __cosf(th), s1);
        xpo[mm][2] = th;
        xpo[mm][3] = v  + (mm ? o3s1 : o3s0) + pb30;
        xpo[mm][4] = td + (mm ? o4s1 : o4s0) + pb31;
    }

    // ---- raw moments: ONE butterfly phase (6 levels), 14 chains ----
    float red[14];
    #pragma unroll
    for (int i = 0; i < 5; ++i) red[i] = xpo[0][i] + xpo[1][i];
    red[5]  = xpo[0][0] * xpo[0][3] + xpo[1][0] * xpo[1][3];
    red[6]  = xpo[0][0] * xpo[0][4] + xpo[1][0] * xpo[1][4];
    red[7]  = xpo[0][1] * xpo[0][3] + xpo[1][1] * xpo[1][3];
    red[8]  = xpo[0][1] * xpo[0][4] + xpo[1][1] * xpo[1][4];
    red[9]  = xpo[0][2] * xpo[0][3] + xpo[1][2] * xpo[1][3];
    red[10] = xpo[0][2] * xpo[0][4] + xpo[1][2] * xpo[1][4];
    red[11] = xpo[0][3] * xpo[0][3] + xpo[1][3] * xpo[1][3];
    red[12] = xpo[0][3] * xpo[0][4] + xpo[1][3] * xpo[1][4];
    red[13] = xpo[0][4] * xpo[0][4] + xpo[1][4] * xpo[1][4];
    #pragma unroll
    for (int off = 1; off < 64; off <<= 1) {
        #pragma unroll
        for (int r = 0; r < 14; ++r)
            red[r] += __shfl_xor(red[r], off, 64);
    }

    // ---- covariances + analytic 2x2 solve ----
    const float inv  = 1.0f / 127.0f;
    const float minv = inv * 0.0078125f; // 1/(127*128)
    float S00 = red[5]  * inv - red[0] * red[3] * minv;
    float S01 = red[6]  * inv - red[0] * red[4] * minv;
    float S10 = red[7]  * inv - red[1] * red[3] * minv;
    float S11 = red[8]  * inv - red[1] * red[4] * minv;
    float S20 = red[9]  * inv - red[2] * red[3] * minv;
    float S21 = red[10] * inv - red[2] * red[4] * minv;
    float S30 = red[11] * inv - red[3] * red[3] * minv;
    float S31 = red[12] * inv - red[3] * red[4] * minv;
    float S40 = S31;
    float S41 = red[13] * inv - red[4] * red[4] * minv;
    float p00 = S30 + diag0, p01 = S31, p10 = S40, p11 = S41 + diag1;
    float rdet = 1.0f / (p00 * p11 - p01 * p10);
    float Ka0 = (p11 * S00 - p01 * S01) * rdet, Kb0 = (p00 * S01 - p10 * S00) * rdet;
    float Ka1 = (p11 * S10 - p01 * S11) * rdet, Kb1 = (p00 * S11 - p10 * S10) * rdet;
    float Ka2 = (p11 * S20 - p01 * S21) * rdet, Kb2 = (p00 * S21 - p10 * S20) * rdet;
    float Ka3 = (p11 * S30 - p01 * S31) * rdet, Kb3 = (p00 * S31 - p10 * S30) * rdet;
    float Ka4 = (p11 * S40 - p01 * S41) * rdet, Kb4 = (p00 * S41 - p10 * S40) * rdet;

    // ---- Kalman update + direct stores (2 owned particles) ----
    #pragma unroll
    for (int mm = 0; mm < 2; ++mm) {
        const int p = c + 32 * (2 * h + mm);
        const float2 yy = *(const float2*)(y_obs + (b * 128 + (size_t)p) * 2);
        float i0 = yy.x - xpo[mm][3];
        float i1 = yy.y - xpo[mm][4];
        float* o = out + (b * 128 + (size_t)p) * 5;
        o[0] = xpo[mm][0] + i0 * Ka0 + i1 * Kb0;
        o[1] = xpo[mm][1] + i0 * Ka1 + i1 * Kb1;
        o[2] = xpo[mm][2] + i0 * Ka2 + i1 * Kb2;
        o[3] = xpo[mm][3] + i0 * Ka3 + i1 * Kb3;
        o[4] = xpo[mm][4] + i0 * Ka4 + i1 * Kb4;
    }
}

extern "C" void kernel_launch(void* const* d_in, const int* in_sizes, int n_in,
                              void* d_out, int out_size, void* d_ws, size_t ws_size,
                              hipStream_t stream) {
    const float* state_old = (const float*)d_in[0];
    const float* y_obs     = (const float*)d_in[1];
    const float* encoding  = (const float*)d_in[2];
    const float* pw1 = (const float*)d_in[3];
    const float* pb1 = (const float*)d_in[4];
    const float* pw2 = (const float*)d_in[5];
    const float* pb2 = (const float*)d_in[6];
    const float* pw3 = (const float*)d_in[7];
    const float* pb3 = (const float*)d_in[8];
    const float* nw1 = (const float*)d_in[9];
    const float* nb1 = (const float*)d_in[10];
    const float* nw2 = (const float*)d_in[11];
    const float* nb2 = (const float*)d_in[12];
    const float* lob = (const float*)d_in[13];
    const float* fob = (const float*)d_in[14];
    float* out = (float*)d_out;

    const int B = 16384;
    dim3 grid(B / NBPB);
    dim3 block(256);
    hipLaunchKernelGGL(ekf_fused, grid, block, 0, stream,
                       state_old, y_obs, encoding,
                       pw1, pb1, pw2, pb2, pw3, pb3,
                       nw1, nb1, nw2, nb2, lob, fob, out);
}